// Round 2
// baseline (270.317 us; speedup 1.0000x reference)
//
#include <hip/hip_runtime.h>
#include <stdint.h>

#define Bc 2
#define Tc 2048
#define Cn 1024
#define Hc 16
#define CAc 64

typedef __attribute__((ext_vector_type(8))) short short8;
typedef __attribute__((ext_vector_type(4))) float f32x4;

__device__ __forceinline__ unsigned short f2bf(float f) {
    unsigned int u = __builtin_bit_cast(unsigned int, f);
    return (unsigned short)((u + 0x7fffu + ((u >> 16) & 1u)) >> 16);
}

// ---------------------------------------------------------------------------
// Kernel A: dtype detection. If x is f32 read as ushorts, even-indexed
// ushorts are mantissa low-halves (random exponent bits). If x is bf16,
// every element has a sane N(0,1) exponent (~0x7F). flag=1 -> bf16.
// ---------------------------------------------------------------------------
__global__ __launch_bounds__(256) void detect_dtype(
    const unsigned short* __restrict__ x, int* __restrict__ flag)
{
    __shared__ int cnt;
    if (threadIdx.x == 0) cnt = 0;
    __syncthreads();
    int c = 0;
#pragma unroll
    for (int i = 0; i < 8; i++) {
        int idx = (threadIdx.x * 8 + i) * 2;  // even indices only
        unsigned short u = x[idx];
        int e = (u >> 7) & 0xFF;
        if (e >= 0x68 && e <= 0x90) c++;       // |v| in [2^-23, 2^17]
    }
    atomicAdd(&cnt, c);
    __syncthreads();
    if (threadIdx.x == 0) *flag = (cnt > 1024) ? 1 : 0;
}

// ---------------------------------------------------------------------------
// Kernel B: normalize x to bf16 (copy if already bf16, convert if f32).
// ---------------------------------------------------------------------------
__global__ __launch_bounds__(256) void convert_x(
    const void* __restrict__ xin, unsigned short* __restrict__ xb,
    const int* __restrict__ flag)
{
    int idx = (blockIdx.x * 256 + threadIdx.x) * 4;
    if (*flag) {
        *(uint2*)(&xb[idx]) = *(const uint2*)((const unsigned short*)xin + idx);
    } else {
        const float* xf = (const float*)xin;
        float4 v = *(const float4*)(xf + idx);
        union { unsigned short s[4]; uint2 u; } p;
        p.s[0] = f2bf(v.x); p.s[1] = f2bf(v.y); p.s[2] = f2bf(v.z); p.s[3] = f2bf(v.w);
        *(uint2*)(&xb[idx]) = p.u;
    }
}

__device__ __forceinline__ unsigned short ld_elem(const void* base, size_t off, int isbf) {
    return isbf ? ((const unsigned short*)base)[off] : f2bf(((const float*)base)[off]);
}

// ---------------------------------------------------------------------------
// Kernel C: transpose weights (either dtype) into bf16, k-contiguous.
// blocks [0,3072): w_q/w_k/w_v per-head [1024][64] -> wT[(proj*16+h)*64+a][1024]
// blocks [3072,4096): w_o [1024][1024] -> w_oT[n][c]
// ---------------------------------------------------------------------------
__global__ __launch_bounds__(256) void transpose_weights(
    const void* __restrict__ wq, const void* __restrict__ wk,
    const void* __restrict__ wv, const void* __restrict__ wo,
    unsigned short* __restrict__ wT, unsigned short* __restrict__ woT,
    const int* __restrict__ flag)
{
    const int isbf = *flag;
    __shared__ unsigned short tile[32][33];
    const int bx = blockIdx.x;
    const int t = threadIdx.x;
    const int tx = t & 31, ty = t >> 5;
    const void* src;
    unsigned short* dst;
    int R, Cw, r0, c0;
    if (bx < 3072) {
        int g = bx >> 6;            // proj*16 + h
        int rem = bx & 63;
        int ct = rem >> 1;          // c-tile 0..31
        int at = rem & 1;           // a-tile 0..1
        int proj = g >> 4, h = g & 15;
        const void* wsel = (proj == 0) ? wq : ((proj == 1) ? wk : wv);
        src = isbf ? (const void*)((const unsigned short*)wsel + (size_t)h * Cn * CAc)
                   : (const void*)((const float*)wsel + (size_t)h * Cn * CAc);
        dst = wT + (size_t)g * CAc * Cn;
        R = Cn; Cw = CAc; r0 = ct * 32; c0 = at * 32;
    } else {
        int rem = bx - 3072;
        src = wo; dst = woT;
        R = Cn; Cw = Cn;
        r0 = (rem >> 5) * 32; c0 = (rem & 31) * 32;
    }
#pragma unroll
    for (int j = 0; j < 4; j++)
        tile[ty + j * 8][tx] = ld_elem(src, (size_t)(r0 + ty + j * 8) * Cw + c0 + tx, isbf);
    __syncthreads();
#pragma unroll
    for (int j = 0; j < 4; j++)
        dst[(size_t)(c0 + ty + j * 8) * R + r0 + tx] = tile[tx][ty + j * 8];
}

// ---------------------------------------------------------------------------
// 128x128 GEMM, K=1024, BK=32, A[m][k] and Bt[n][k] both bf16 k-contiguous.
// MODE 0: QKV epilogue (o0=q [B,H,T,Ca], o1=k [B,H,T,Ca], o2=vT [B,H,Ca,T])
// MODE 1: out epilogue (o0[m][n], N=1024; bf16 or f32 per flag)
// ---------------------------------------------------------------------------
template <int MODE>
__global__ __launch_bounds__(256) void gemm128(
    const unsigned short* __restrict__ Amat,
    const unsigned short* __restrict__ Bt,
    void* __restrict__ o0,
    unsigned short* __restrict__ o1,
    unsigned short* __restrict__ o2,
    const int* __restrict__ flag)
{
    const int LDA = 40;  // 32 + 8 pad elems -> 80B row stride (16B-aligned rows)
    __shared__ alignas(16) unsigned short Al[128 * LDA];
    __shared__ alignas(16) unsigned short Bl[128 * LDA];
    const int tid = threadIdx.x;
    const int wave = tid >> 6, lane = tid & 63;
    const int l15 = lane & 15, quad = lane >> 4;
    const int mBase = blockIdx.y * 128, nBase = blockIdx.x * 128;
    const int mOff = (wave & 1) * 64, nOff = (wave >> 1) * 64;

    f32x4 acc[4][4];
#pragma unroll
    for (int i = 0; i < 4; i++)
#pragma unroll
        for (int j = 0; j < 4; j++)
            acc[i][j] = (f32x4){0.f, 0.f, 0.f, 0.f};

    for (int k0 = 0; k0 < Cn; k0 += 32) {
#pragma unroll
        for (int c = 0; c < 2; c++) {
            int idx = c * 256 + tid;
            int row = idx >> 2, col = (idx & 3) * 8;
            *(uint4*)(&Al[row * LDA + col]) =
                *(const uint4*)(&Amat[(size_t)(mBase + row) * Cn + k0 + col]);
            *(uint4*)(&Bl[row * LDA + col]) =
                *(const uint4*)(&Bt[(size_t)(nBase + row) * Cn + k0 + col]);
        }
        __syncthreads();
        short8 af[4], bfr[4];
#pragma unroll
        for (int i = 0; i < 4; i++)
            af[i] = *(const short8*)(&Al[(mOff + i * 16 + l15) * LDA + quad * 8]);
#pragma unroll
        for (int j = 0; j < 4; j++)
            bfr[j] = *(const short8*)(&Bl[(nOff + j * 16 + l15) * LDA + quad * 8]);
#pragma unroll
        for (int i = 0; i < 4; i++)
#pragma unroll
            for (int j = 0; j < 4; j++)
                acc[i][j] = __builtin_amdgcn_mfma_f32_16x16x32_bf16(af[i], bfr[j], acc[i][j], 0, 0, 0);
        __syncthreads();
    }

    if constexpr (MODE == 0) {
#pragma unroll
        for (int i = 0; i < 4; i++) {
            int m0 = mBase + mOff + i * 16 + quad * 4;
            int b = m0 >> 11, t0 = m0 & (Tc - 1);
#pragma unroll
            for (int j = 0; j < 4; j++) {
                int n = nBase + nOff + j * 16 + l15;
                int proj = n >> 10, h = (n >> 6) & 15, a = n & 63;
                if (proj == 2) {
                    union { unsigned short s[4]; uint2 v; } pk;
#pragma unroll
                    for (int r = 0; r < 4; r++) pk.s[r] = f2bf(acc[i][j][r]);
                    *(uint2*)(&((unsigned short*)o0)[((size_t)2 * Hc * Tc * CAc) * 0] ) ; // no-op guard
                    *(uint2*)(&o2[((size_t)(b * Hc + h) * CAc + a) * Tc + t0]) = pk.v;
                } else {
                    unsigned short* dst = (proj == 0) ? (unsigned short*)o0 : o1;
                    size_t base = ((size_t)(b * Hc + h) * Tc + t0) * CAc + a;
#pragma unroll
                    for (int r = 0; r < 4; r++)
                        dst[base + (size_t)r * CAc] = f2bf(acc[i][j][r]);
                }
            }
        }
    } else {
        const int isbf = *flag;
#pragma unroll
        for (int i = 0; i < 4; i++) {
            int m0 = mBase + mOff + i * 16 + quad * 4;
#pragma unroll
            for (int j = 0; j < 4; j++) {
                int n = nBase + nOff + j * 16 + l15;
                if (isbf) {
#pragma unroll
                    for (int r = 0; r < 4; r++)
                        ((unsigned short*)o0)[(size_t)(m0 + r) * Cn + n] = f2bf(acc[i][j][r]);
                } else {
#pragma unroll
                    for (int r = 0; r < 4; r++)
                        ((float*)o0)[(size_t)(m0 + r) * Cn + n] = acc[i][j][r];
                }
            }
        }
    }
}

// ---------------------------------------------------------------------------
// Flash attention, causal. One block per (b,h,q-tile of 64). 4 waves; wave w
// owns q rows [q0+16w, q0+16w+16). Masks use -1e30f (no inf arithmetic).
// ---------------------------------------------------------------------------
__global__ __launch_bounds__(256) void attn64(
    const unsigned short* __restrict__ q,
    const unsigned short* __restrict__ k,
    const unsigned short* __restrict__ vT,
    unsigned short* __restrict__ y)
{
    const int LDK = 72;  // 64 + 8 pad
    __shared__ alignas(16) unsigned short Kl[64 * LDK];
    __shared__ alignas(16) unsigned short Vl[64 * LDK];
    __shared__ alignas(16) unsigned short Pl[4][16 * LDK];
    const int bx = blockIdx.x;
    const int qt = bx & 31, h = (bx >> 5) & 15, b = bx >> 9;
    const int tid = threadIdx.x;
    const int wave = tid >> 6, lane = tid & 63;
    const int l15 = lane & 15, quad = lane >> 4;
    const int q0 = qt * 64;
    const int m0w = q0 + wave * 16;
    const size_t bh = (size_t)(b * Hc + h);
    const unsigned short* qh = q + bh * Tc * CAc;
    const unsigned short* kh = k + bh * Tc * CAc;
    const unsigned short* vh = vT + bh * CAc * Tc;

    short8 qf[2];
#pragma unroll
    for (int s = 0; s < 2; s++)
        qf[s] = *(const short8*)(&qh[(size_t)(m0w + l15) * CAc + s * 32 + quad * 8]);

    f32x4 oacc[4];
#pragma unroll
    for (int j2 = 0; j2 < 4; j2++) oacc[j2] = (f32x4){0.f, 0.f, 0.f, 0.f};
    float mrow[4], lrow[4];
#pragma unroll
    for (int r = 0; r < 4; r++) { mrow[r] = -1e30f; lrow[r] = 0.f; }

    for (int kt = 0; kt <= qt; kt++) {
        const int k0 = kt * 64;
#pragma unroll
        for (int c = 0; c < 2; c++) {
            int idx = c * 256 + tid;
            int row = idx >> 3, col = (idx & 7) * 8;
            *(uint4*)(&Kl[row * LDK + col]) = *(const uint4*)(&kh[(size_t)(k0 + row) * CAc + col]);
            *(uint4*)(&Vl[row * LDK + col]) = *(const uint4*)(&vh[(size_t)row * Tc + k0 + col]);
        }
        __syncthreads();

        // S = Q K^T (16x64 per wave), causal mask then scale
        float sv[4][4];
#pragma unroll
        for (int j = 0; j < 4; j++) {
            f32x4 z = (f32x4){0.f, 0.f, 0.f, 0.f};
            short8 kf0 = *(const short8*)(&Kl[(j * 16 + l15) * LDK + quad * 8]);
            short8 kf1 = *(const short8*)(&Kl[(j * 16 + l15) * LDK + 32 + quad * 8]);
            z = __builtin_amdgcn_mfma_f32_16x16x32_bf16(qf[0], kf0, z, 0, 0, 0);
            z = __builtin_amdgcn_mfma_f32_16x16x32_bf16(qf[1], kf1, z, 0, 0, 0);
            int cg = k0 + j * 16 + l15;
#pragma unroll
            for (int r = 0; r < 4; r++) {
                int rg = m0w + quad * 4 + r;
                sv[j][r] = (cg <= rg) ? z[r] * 0.125f : -1e30f;
            }
        }
        // online softmax: rows quad*4+r, reduce across the 16 l15 lanes
        float nm[4];
#pragma unroll
        for (int r = 0; r < 4; r++)
            nm[r] = fmaxf(fmaxf(fmaxf(sv[0][r], sv[1][r]), fmaxf(sv[2][r], sv[3][r])), mrow[r]);
#pragma unroll
        for (int off = 1; off < 16; off <<= 1)
#pragma unroll
            for (int r = 0; r < 4; r++)
                nm[r] = fmaxf(nm[r], __shfl_xor(nm[r], off, 64));
        float alpha[4], rs[4];
#pragma unroll
        for (int r = 0; r < 4; r++) {
            alpha[r] = __expf(mrow[r] - nm[r]);   // first tile: exp(-2e30) = 0
            mrow[r] = nm[r];
            rs[r] = 0.f;
        }
#pragma unroll
        for (int j = 0; j < 4; j++)
#pragma unroll
            for (int r = 0; r < 4; r++) {
                float p = __expf(sv[j][r] - mrow[r]);  // masked -> exp(-1e30) = 0
                sv[j][r] = p;
                rs[r] += p;
            }
#pragma unroll
        for (int off = 1; off < 16; off <<= 1)
#pragma unroll
            for (int r = 0; r < 4; r++)
                rs[r] += __shfl_xor(rs[r], off, 64);
#pragma unroll
        for (int r = 0; r < 4; r++)
            lrow[r] = lrow[r] * alpha[r] + rs[r];
#pragma unroll
        for (int j2 = 0; j2 < 4; j2++)
#pragma unroll
            for (int r = 0; r < 4; r++)
                oacc[j2][r] *= alpha[r];

        // P: C-layout regs -> per-wave LDS -> A-layout frags (same-wave order)
#pragma unroll
        for (int j = 0; j < 4; j++)
#pragma unroll
            for (int r = 0; r < 4; r++)
                Pl[wave][(quad * 4 + r) * LDK + j * 16 + l15] = f2bf(sv[j][r]);
#pragma unroll
        for (int s = 0; s < 2; s++) {
            short8 pa = *(const short8*)(&Pl[wave][l15 * LDK + s * 32 + quad * 8]);
#pragma unroll
            for (int j2 = 0; j2 < 4; j2++) {
                short8 vb = *(const short8*)(&Vl[(j2 * 16 + l15) * LDK + s * 32 + quad * 8]);
                oacc[j2] = __builtin_amdgcn_mfma_f32_16x16x32_bf16(pa, vb, oacc[j2], 0, 0, 0);
            }
        }
        __syncthreads();   // protect Kl/Vl before next stage
    }

    // epilogue: y[b][t][h*64 + a], normalized by row sum
#pragma unroll
    for (int j2 = 0; j2 < 4; j2++) {
#pragma unroll
        for (int r = 0; r < 4; r++) {
            int t = m0w + quad * 4 + r;
            y[((size_t)b * Tc + t) * Cn + h * CAc + j2 * 16 + l15] = f2bf(oacc[j2][r] / lrow[r]);
        }
    }
}

// ---------------------------------------------------------------------------
extern "C" void kernel_launch(void* const* d_in, const int* in_sizes, int n_in,
                              void* d_out, int out_size, void* d_ws, size_t ws_size,
                              hipStream_t stream) {
    const void* x  = d_in[0];
    const void* wq = d_in[1];
    const void* wk = d_in[2];
    const void* wv = d_in[3];
    const void* wo = d_in[4];
    char* ws = (char*)d_ws;
    // ws layout (MB): flag@0 | wT@1(6) | woT@7(2) | xb@9(8) | q@17(8) | k@25(8) | vT@33(8) | y@41(8)
    int* flag = (int*)(ws);
    unsigned short* wT  = (unsigned short*)(ws + ((size_t)1 << 20));
    unsigned short* woT = (unsigned short*)(ws + ((size_t)7 << 20));
    unsigned short* xb  = (unsigned short*)(ws + ((size_t)9 << 20));
    unsigned short* qb  = (unsigned short*)(ws + ((size_t)17 << 20));
    unsigned short* kb  = (unsigned short*)(ws + ((size_t)25 << 20));
    unsigned short* vTb = (unsigned short*)(ws + ((size_t)33 << 20));
    unsigned short* yb  = (unsigned short*)(ws + ((size_t)41 << 20));

    detect_dtype<<<dim3(1), dim3(256), 0, stream>>>((const unsigned short*)x, flag);
    convert_x<<<dim3(4096), dim3(256), 0, stream>>>(x, xb, flag);
    transpose_weights<<<dim3(4096), dim3(256), 0, stream>>>(wq, wk, wv, wo, wT, woT, flag);
    gemm128<0><<<dim3(24, 32), dim3(256), 0, stream>>>(xb, wT, qb, kb, vTb, flag);
    attn64<<<dim3(1024), dim3(256), 0, stream>>>(qb, kb, vTb, yb);
    gemm128<1><<<dim3(8, 32), dim3(256), 0, stream>>>(yb, woT, d_out, nullptr, nullptr, flag);
}